// Round 6
// baseline (2679.204 us; speedup 1.0000x reference)
//
#include <hip/hip_runtime.h>

typedef __bf16 bf16;
typedef __attribute__((ext_vector_type(8))) __bf16 bf16x8;
typedef __attribute__((ext_vector_type(4))) __bf16 bf16x4;
typedef __attribute__((ext_vector_type(2))) __bf16 bf16x2;
typedef __attribute__((ext_vector_type(4))) float f32x4;

#define BM 128
#define BN 128
#define BK 64

__device__ __forceinline__ void async_cp16(const bf16* g, bf16* l) {
    __builtin_amdgcn_global_load_lds((const __attribute__((address_space(1))) void*)g,
                                     (__attribute__((address_space(3))) void*)l, 16, 0, 0);
}
__device__ __forceinline__ float sigm(float x) { return 1.0f / (1.0f + __expf(-x)); }

// C[M,N] = A[M,K] @ B[N,K]^T (+ optional second product A2@B2^T), fused epilogues.
// EPI: 0 = raw f32 out; 1 = +bias[n], bf16 out; 2 = GRU combine -> s1 (bf16);
//      4 = gate mix -> s2 (bf16); 5 = +bias[n], f32 out.
// zrh: [M/16, 1536] f32 chunk-local pre-activations (z|r|h) for EPI==2.
template<int EPI, bool DUAL>
__global__ __launch_bounds__(256, 2)
void gemm_bt(const bf16* __restrict__ A, const bf16* __restrict__ Bw,
             const bf16* __restrict__ A2, const bf16* __restrict__ B2,
             int M, int N, int K,
             float* __restrict__ outf, bf16* __restrict__ outb,
             const float* __restrict__ bias,
             const float* __restrict__ zrh, const float* __restrict__ bh,
             const float* __restrict__ bz,
             const float* __restrict__ zs, const float* __restrict__ S0,
             const bf16* __restrict__ s1p, const bf16* __restrict__ c2p)
{
    __shared__ bf16 As[BM * BK];
    __shared__ bf16 Bs[BN * BK];
    const int tid  = threadIdx.x;
    const int lane = tid & 63;
    const int wave = tid >> 6;
    const int wr = wave >> 1, wc = wave & 1;
    const size_t arow0 = (size_t)blockIdx.y * BM;   // output rows
    const size_t brow0 = (size_t)blockIdx.x * BN;   // output cols (rows of B)
    const int srow = tid >> 3;        // staging row within 32-row chunk
    const int scol = (tid & 7) * 8;   // staging col (elements)

    f32x4 acc[4][4];
    const f32x4 zero = {0.f, 0.f, 0.f, 0.f};
#pragma unroll
    for (int i = 0; i < 4; i++)
#pragma unroll
        for (int j = 0; j < 4; j++) acc[i][j] = zero;

    const int KT  = K / BK;
    const int TKT = DUAL ? 2 * KT : KT;
    for (int kt = 0; kt < TKT; ++kt) {
        const bf16* Ag; const bf16* Bg; int k0;
        if (!DUAL || kt < KT) { Ag = A;  Bg = Bw; k0 = kt * BK; }
        else                  { Ag = A2; Bg = B2; k0 = (kt - KT) * BK; }
        const bf16* ga = Ag + (arow0 + srow) * (size_t)K + k0 + scol;
        const bf16* gb = Bg + (brow0 + srow) * (size_t)K + k0 + scol;
        __syncthreads();   // previous compute done before LDS overwrite
#pragma unroll
        for (int i = 0; i < 4; i++) {
            async_cp16(ga + (size_t)(i * 32) * K, As + wave * 512 + i * 2048);
            async_cp16(gb + (size_t)(i * 32) * K, Bs + wave * 512 + i * 2048);
        }
        __syncthreads();   // compiler drains vmcnt before barrier
        const bf16* Ab = As + (wr * 64 + (lane & 15)) * BK + ((lane >> 4) * 8);
        const bf16* Bb = Bs + (wc * 64 + (lane & 15)) * BK + ((lane >> 4) * 8);
#pragma unroll
        for (int kk = 0; kk < BK; kk += 32) {
            bf16x8 av[4], bv[4];
#pragma unroll
            for (int i = 0; i < 4; i++) {
                av[i] = *(const bf16x8*)(Ab + i * 16 * BK + kk);
                bv[i] = *(const bf16x8*)(Bb + i * 16 * BK + kk);
            }
#pragma unroll
            for (int mi = 0; mi < 4; mi++)
#pragma unroll
                for (int ni = 0; ni < 4; ni++)
                    acc[mi][ni] = __builtin_amdgcn_mfma_f32_16x16x32_bf16(av[mi], bv[ni], acc[mi][ni], 0, 0, 0);
        }
    }

    const int mbase = (int)arow0 + wr * 64;
    const int nbase = (int)brow0 + wc * 64;
#pragma unroll
    for (int mi = 0; mi < 4; mi++) {
#pragma unroll
        for (int ni = 0; ni < 4; ni++) {
            f32x4 v = acc[mi][ni];
            const int n  = nbase + ni * 16 + (lane & 15);
            const int m0 = mbase + mi * 16 + (lane >> 4) * 4;
#pragma unroll
            for (int r = 0; r < 4; r++) {
                const int m = m0 + r;
                const float val = v[r];
                const size_t oidx = (size_t)m * N + n;
                if constexpr (EPI == 0) {
                    outf[oidx] = val;
                } else if constexpr (EPI == 1) {
                    outb[oidx] = (bf16)(val + bias[n]);
                } else if constexpr (EPI == 2) {
                    const int brow_ = m >> 4, node = m & 15;
                    const float cand = tanhf(val + zrh[(size_t)brow_ * 1536 + 1024 + n] + bh[n]);
                    const float z = sigm(zrh[(size_t)brow_ * 1536 + n] + zs[node * 512 + n] + bz[n]);
                    const float s0v = S0[node * 512 + n];
                    outb[oidx] = (bf16)((1.f - z) * s0v + z * cand);
                } else if constexpr (EPI == 4) {
                    const float g = sigm(val + bias[n]);
                    outb[oidx] = (bf16)(g * (float)s1p[oidx] + (1.f - g) * (float)c2p[oidx]);
                } else {
                    outf[oidx] = val + bias[n];
                }
            }
        }
    }
}

// f32 [rows, src_ld] column-slice [col0, col0+cols) -> contiguous bf16 [rows, cols]
__global__ __launch_bounds__(256)
void cvt_slice(bf16* __restrict__ dst, const float* __restrict__ src,
               int cols, int src_ld, int col0)
{
    const size_t i = ((size_t)blockIdx.x * 256 + threadIdx.x) * 4;
    const int r = (int)(i / cols), c = (int)(i % cols);
    float4 v = *(const float4*)(src + (size_t)r * src_ld + col0 + c);
    bf16x4 o; o[0] = (bf16)v.x; o[1] = (bf16)v.y; o[2] = (bf16)v.z; o[3] = (bf16)v.w;
    *(bf16x4*)(dst + i) = o;
}

// zs[n,:] = S0[n,:] @ Wz[:, :512].T ; rs[n,:] = S0[n,:] @ Wr[:, :512].T  (f32)
__global__ __launch_bounds__(256)
void node_proj_kernel(const float* __restrict__ S0, const float* __restrict__ Wz,
                      const float* __restrict__ Wr, float* __restrict__ zs,
                      float* __restrict__ rs)
{
    alignas(16) __shared__ float srow[512];
    const int tid = threadIdx.x;
    const int which = blockIdx.x >> 4;
    const int n = blockIdx.x & 15;
    const float* W = which ? Wr : Wz;
    float* out = which ? rs : zs;
    for (int i = tid; i < 512; i += 256) srow[i] = S0[n * 512 + i];
    __syncthreads();
    for (int j = tid; j < 512; j += 256) {
        const float4* wrow = (const float4*)(W + (size_t)j * 1024);
        float acc = 0.f;
#pragma unroll 4
        for (int k = 0; k < 128; k++) {
            float4 wv = wrow[k];
            float4 sv = *(const float4*)(srow + k * 4);
            acc += sv.x * wv.x + sv.y * wv.y + sv.z * wv.z + sv.w * wv.w;
        }
        out[n * 512 + j] = acc;
    }
}

// Ah[b,n,:] = sigmoid(zrh[b,512+d] + rs[n,d] + br[d]) * S0[n,d]  (chunk-local b)
__global__ __launch_bounds__(256)
void gru_r_kernel(const float* __restrict__ zrh, const float* __restrict__ rs,
                  const float* __restrict__ br, const float* __restrict__ S0,
                  bf16* __restrict__ Ah)
{
    const size_t bn_ = blockIdx.x;
    const int b = (int)(bn_ >> 4), n = (int)(bn_ & 15);
    const int d = threadIdx.x * 2;
    const float2 rxv = *(const float2*)(zrh + (size_t)b * 1536 + 512 + d);
    const float2 rsv = *(const float2*)(rs + n * 512 + d);
    const float2 brv = *(const float2*)(br + d);
    const float2 s0v = *(const float2*)(S0 + n * 512 + d);
    bf16x2 o;
    o[0] = (bf16)(sigm(rxv.x + rsv.x + brv.x) * s0v.x);
    o[1] = (bf16)(sigm(rxv.y + rsv.y + brv.y) * s0v.y);
    *(bf16x2*)(Ah + bn_ * 512 + d) = o;
}

// Per-batch 16-node MHA (H=4, dh=128). One block per b, wave h per head.
__global__ __launch_bounds__(256, 2)
void attn_kernel(const bf16* __restrict__ qkv, bf16* __restrict__ ctx)
{
    __shared__ bf16 sq[16 * 1544];          // row-padded (+8 elems) vs 1536
    __shared__ float attn_s[4][16][16];
    const int tid = threadIdx.x;
    const int lane = tid & 63, wave = tid >> 6;
    const size_t b = blockIdx.x;
    const bf16* src = qkv + b * 24576;
    for (int c = tid; c < 3072; c += 256) {
        int row = c / 192, col = c % 192;
        *(uint4*)(sq + row * 1544 + col * 8) = *(const uint4*)(src + (size_t)c * 8);
    }
    __syncthreads();
    const int h = wave;
#pragma unroll
    for (int t = 0; t < 4; t++) {
        int idx = t * 64 + lane;
        int i = idx >> 4, j = idx & 15;
        const bf16* qp = sq + i * 1544 + h * 128;
        const bf16* kp = sq + j * 1544 + 512 + h * 128;
        float s = 0.f;
#pragma unroll
        for (int k8 = 0; k8 < 128; k8 += 8) {
            bf16x8 qv = *(const bf16x8*)(qp + k8);
            bf16x8 kv = *(const bf16x8*)(kp + k8);
#pragma unroll
            for (int u = 0; u < 8; u++) s += (float)qv[u] * (float)kv[u];
        }
        attn_s[h][i][j] = s * 0.08838834764831845f;   // 1/sqrt(128)
    }
    __syncthreads();
    if (lane < 16) {
        float* row = &attn_s[h][lane][0];
        float mx = row[0];
#pragma unroll
        for (int j2 = 1; j2 < 16; j2++) mx = fmaxf(mx, row[j2]);
        float sum = 0.f;
#pragma unroll
        for (int j2 = 0; j2 < 16; j2++) { float pp = __expf(row[j2] - mx); row[j2] = pp; sum += pp; }
        float inv = 1.f / sum;
#pragma unroll
        for (int j2 = 0; j2 < 16; j2++) row[j2] *= inv;
    }
    __syncthreads();
    bf16* outp = ctx + b * 8192;
    for (int e = tid; e < 8192; e += 256) {
        int i = e >> 9, d = e & 511, h2 = d >> 7;
        float s = 0.f;
#pragma unroll
        for (int j2 = 0; j2 < 16; j2++) s += attn_s[h2][i][j2] * (float)sq[j2 * 1544 + 1024 + d];
        outp[i * 512 + d] = (bf16)s;
    }
}

extern "C" void kernel_launch(void* const* d_in, const int* in_sizes, int n_in,
                              void* d_out, int out_size, void* d_ws, size_t ws_size,
                              hipStream_t stream)
{
    (void)in_sizes; (void)n_in; (void)out_size;
    const float* x    = (const float*)d_in[0];
    const float* W_in = (const float*)d_in[1];
    const float* b_in = (const float*)d_in[2];
    const float* S0   = (const float*)d_in[3];
    const float* Wz   = (const float*)d_in[4];
    const float* bz   = (const float*)d_in[5];
    const float* Wr   = (const float*)d_in[6];
    const float* br   = (const float*)d_in[7];
    const float* Wh   = (const float*)d_in[8];
    const float* bh   = (const float*)d_in[9];
    const float* Wqkv = (const float*)d_in[10];
    const float* bqkv = (const float*)d_in[11];
    const float* Wo   = (const float*)d_in[12];
    const float* bo   = (const float*)d_in[13];
    const float* Wg   = (const float*)d_in[14];
    const float* bg   = (const float*)d_in[15];
    const float* Wout = (const float*)d_in[16];
    const float* bout = (const float*)d_in[17];
    float* out = (float*)d_out;
    char* p = (char*)d_ws;

    // ---- ws-size-adaptive layout: fixed region + per-chunk arena ----
    // fixed: s2(128Mi) x_bf(8Mi) weights(~21.5Mi) zs/rs(64Ki) = ~158 MiB
    size_t off = 0;
    auto alloc = [&](size_t bytes) { size_t o = off; off += (bytes + 1023) & ~size_t(1023); return o; };
    const size_t o_s2      = alloc(131072ull * 512 * 2);
    const size_t o_xbf     = alloc(8192ull * 512 * 2);
    const size_t o_Win     = alloc(512ull * 512 * 2);
    const size_t o_W3x     = alloc(1536ull * 512 * 2);
    const size_t o_Whs     = alloc(512ull * 512 * 2);
    const size_t o_Wqkv    = alloc(1536ull * 512 * 2);
    const size_t o_Wo      = alloc(512ull * 512 * 2);
    const size_t o_Wgs     = alloc(512ull * 512 * 2);
    const size_t o_Wgc     = alloc(512ull * 512 * 2);
    const size_t o_Wout    = alloc(1024ull * 8192 * 2);
    const size_t o_zs      = alloc(16ull * 512 * 4);
    const size_t o_rs      = alloc(16ull * 512 * 4);
    const size_t fixed_end = off;

    // per-chunk arena, C batches: xp(C*1Ki) zrh(C*6Ki) Ah(C*16Ki) s1(C*16Ki)
    // qkv(C*48Ki) ctx(C*16Ki) ctx2(C*16Ki) = C*119 KiB
    const size_t per_c = 1024 + 6144 + 16384 + 16384 + 49152 + 16384 + 16384;
    int C = 0;
    for (int cand : {2048, 1024, 512, 256})   // cap 2048: keep footprint <=~400MiB
        if (fixed_end + (size_t)cand * per_c <= ws_size) { C = cand; break; }
    if (C == 0) return;  // ws too small for min footprint: fail cleanly, don't fault

    const size_t o_xp   = fixed_end;
    const size_t o_zrh  = o_xp   + (size_t)C * 1024;
    const size_t o_Ah   = o_zrh  + (size_t)C * 6144;
    const size_t o_s1   = o_Ah   + (size_t)C * 16384;
    const size_t o_qkv  = o_s1   + (size_t)C * 16384;
    const size_t o_ctx  = o_qkv  + (size_t)C * 49152;
    const size_t o_ctx2 = o_ctx  + (size_t)C * 16384;

    bf16*  s2      = (bf16*)(p + o_s2);
    bf16*  x_bf    = (bf16*)(p + o_xbf);
    bf16*  Win_bf  = (bf16*)(p + o_Win);
    bf16*  W3x     = (bf16*)(p + o_W3x);
    bf16*  Whs     = (bf16*)(p + o_Whs);
    bf16*  Wqkv_bf = (bf16*)(p + o_Wqkv);
    bf16*  Wo_bf   = (bf16*)(p + o_Wo);
    bf16*  Wgs     = (bf16*)(p + o_Wgs);
    bf16*  Wgc     = (bf16*)(p + o_Wgc);
    bf16*  Wout_bf = (bf16*)(p + o_Wout);
    float* zs      = (float*)(p + o_zs);
    float* rs      = (float*)(p + o_rs);
    bf16*  xp_c    = (bf16*)(p + o_xp);
    float* zrh_c   = (float*)(p + o_zrh);
    bf16*  Ah_c    = (bf16*)(p + o_Ah);
    bf16*  s1_c    = (bf16*)(p + o_s1);
    bf16*  qkv_c   = (bf16*)(p + o_qkv);
    bf16*  ctx_c   = (bf16*)(p + o_ctx);
    bf16*  ctx2_c  = (bf16*)(p + o_ctx2);

    auto cvtl = [&](bf16* dst, const float* src, int rows, int cols, int ld, int c0) {
        cvt_slice<<<dim3(rows * cols / 1024), dim3(256), 0, stream>>>(dst, src, cols, ld, c0);
    };
    // weight/x conversions (once)
    cvtl(x_bf, x, 8192, 512, 512, 0);
    cvtl(Win_bf, W_in, 512, 512, 512, 0);
    cvtl(W3x,              Wz, 512, 512, 1024, 512);   // rows 0-511: Wz[:,512:]
    cvtl(W3x + 512 * 512,  Wr, 512, 512, 1024, 512);   // rows 512-1023: Wr[:,512:]
    cvtl(W3x + 1024 * 512, Wh, 512, 512, 1024, 512);   // rows 1024-1535: Wh[:,512:]
    cvtl(Whs, Wh, 512, 512, 1024, 0);
    cvtl(Wqkv_bf, Wqkv, 1536, 512, 512, 0);
    cvtl(Wo_bf, Wo, 512, 512, 512, 0);
    cvtl(Wgs, Wg, 512, 512, 1024, 0);
    cvtl(Wgc, Wg, 512, 512, 1024, 512);
    cvtl(Wout_bf, Wout, 1024, 8192, 8192, 0);
    node_proj_kernel<<<dim3(32), dim3(256), 0, stream>>>(S0, Wz, Wr, zs, rs);

    const int n_chunks = 8192 / C;
    for (int c = 0; c < n_chunks; ++c) {
        const size_t B0 = (size_t)c * C;
        const int Mc = C * 16;
        // xp = x @ W_in.T + b_in  (bf16)
        gemm_bt<1, false><<<dim3(4, C / 128), dim3(256), 0, stream>>>(
            x_bf + B0 * 512, Win_bf, nullptr, nullptr, C, 512, 512,
            nullptr, xp_c, b_in, nullptr, nullptr, nullptr, nullptr, nullptr, nullptr, nullptr);
        // zrh = xp @ [Wzx|Wrx|Whx]^T  (f32 pre-activations, biases folded later)
        gemm_bt<0, false><<<dim3(12, C / 128), dim3(256), 0, stream>>>(
            xp_c, W3x, nullptr, nullptr, C, 1536, 512,
            zrh_c, nullptr, nullptr, nullptr, nullptr, nullptr, nullptr, nullptr, nullptr, nullptr);
        // Ah = sigmoid(r_pre)*S0
        gru_r_kernel<<<dim3(C * 16), dim3(256), 0, stream>>>(zrh_c, rs, br, S0, Ah_c);
        // s1 = (1-z)*S0 + z*tanh(Ah @ Whs.T + h_pre + bh)
        gemm_bt<2, false><<<dim3(4, Mc / 128), dim3(256), 0, stream>>>(
            Ah_c, Whs, nullptr, nullptr, Mc, 512, 512,
            nullptr, s1_c, nullptr, zrh_c, bh, bz, zs, S0, nullptr, nullptr);
        // qkv = s1 @ Wqkv.T + bqkv
        gemm_bt<1, false><<<dim3(12, Mc / 128), dim3(256), 0, stream>>>(
            s1_c, Wqkv_bf, nullptr, nullptr, Mc, 1536, 512,
            nullptr, qkv_c, bqkv, nullptr, nullptr, nullptr, nullptr, nullptr, nullptr, nullptr);
        // ctx = MHA(qkv)
        attn_kernel<<<dim3(C), dim3(256), 0, stream>>>(qkv_c, ctx_c);
        // ctx2 = ctx @ Wo.T + bo
        gemm_bt<1, false><<<dim3(4, Mc / 128), dim3(256), 0, stream>>>(
            ctx_c, Wo_bf, nullptr, nullptr, Mc, 512, 512,
            nullptr, ctx2_c, bo, nullptr, nullptr, nullptr, nullptr, nullptr, nullptr, nullptr);
        // g = sigmoid(s1@Wgs.T + ctx2@Wgc.T + bg); s2 = g*s1 + (1-g)*ctx2
        gemm_bt<4, true><<<dim3(4, Mc / 128), dim3(256), 0, stream>>>(
            s1_c, Wgs, ctx2_c, Wgc, Mc, 512, 512,
            nullptr, s2 + B0 * 8192, bg, nullptr, nullptr, nullptr, nullptr, nullptr, s1_c, ctx2_c);
    }
    // out = pooled @ W_out.T + b_out   (pooled = s2 viewed [8192, 8192])
    gemm_bt<5, false><<<dim3(8, 64), dim3(256), 0, stream>>>(
        s2, Wout_bf, nullptr, nullptr, 8192, 1024, 8192,
        out, nullptr, bout, nullptr, nullptr, nullptr, nullptr, nullptr, nullptr, nullptr);
}